// Round 4
// baseline (93.080 us; speedup 1.0000x reference)
//
#include <hip/hip_runtime.h>

#define CV_H 96
#define CV_W 128
#define CV_C 16
#define CV_K 7
#define CV_D 64
#define CV_EPS 1e-8f
#define CV_HW (CV_H * CV_W)
#define CV_NBLK 768          // = (K+1)*H ; must stay <= resident capacity (1024 @128 VGPR)

typedef _Float16 v2h __attribute__((ext_vector_type(2)));
typedef _Float16 v8h __attribute__((ext_vector_type(8)));

#if __has_builtin(__builtin_amdgcn_fdot2)
#define FDOT2(a, b, c) __builtin_amdgcn_fdot2((a), (b), (c), false)
#else
#define FDOT2(a, b, c) ((float)(a)[0] * (float)(b)[0] + (float)(a)[1] * (float)(b)[1] + (c))
#endif

__device__ __forceinline__ float dot16h(v8h a0, v8h a1, v8h b0, v8h b1) {
    const v2h* pa0 = (const v2h*)&a0; const v2h* pb0 = (const v2h*)&b0;
    const v2h* pa1 = (const v2h*)&a1; const v2h* pb1 = (const v2h*)&b1;
    float s = 0.f;
#pragma unroll
    for (int i = 0; i < 4; ++i) s = FDOT2(pa0[i], pb0[i], s);
#pragma unroll
    for (int i = 0; i < 4; ++i) s = FDOT2(pa1[i], pb1[i], s);
    return s;
}

// ---------------------------------------------------------------------------
// Single fused kernel.
// Phase A: each block transposes one (view,row): [C][W] f32 -> [W][C] fp16.
// Phase B: every block redundantly computes the 7 fused projection matrices
//          M[k]=[A|b] into LDS (A=(Ks@E)[:3,:3]@invK[:3,:3], b=(Ks@E)[:3,3]),
//          plus log-depth params.  cam = depth*(A@[x+.5,y+.5,1]) + b.
// Grid barrier: atomic counter + spin (all 768 blocks resident by
//          __launch_bounds__(256,4) -> >=4 blocks/CU -> 1024 capacity).
// Phase C: block = 8x8 px tile x 16 depths; each thread: 4 depths for one
//          pixel, 7 views; q = A@pix hoisted across the 4 depth samples.
// ---------------------------------------------------------------------------
__global__ __launch_bounds__(256, 4) void cv_fused(
    const float* __restrict__ cur, const float* __restrict__ src,
    const float* __restrict__ extr, const float* __restrict__ Ks,
    const float* __restrict__ invK, const float* __restrict__ minD,
    const float* __restrict__ maxD,
    _Float16* __restrict__ srcT, _Float16* __restrict__ curT,
    unsigned* __restrict__ counter, float* __restrict__ out) {
    const int b = blockIdx.x;
    const int t = threadIdx.x;

    __shared__ float Ml[CV_K][12];
    __shared__ float dparams[2];

    // ---- Phase A: transpose+convert one (g,h) row ----
    {
        const int g = b / CV_H, h = b % CV_H;
        const float* rowBase = (g < CV_K) ? src + (size_t)g * CV_C * CV_HW + h * CV_W
                                          : cur + h * CV_W;
        __shared__ float lds[CV_C][CV_W + 2];
#pragma unroll
        for (int i = 0; i < 2; ++i) {
            int f = t + i * 256, c = f >> 5, w4 = (f & 31) << 2;
            float4 v = *(const float4*)(rowBase + (size_t)c * CV_HW + w4);
            lds[c][w4 + 0] = v.x; lds[c][w4 + 1] = v.y;
            lds[c][w4 + 2] = v.z; lds[c][w4 + 3] = v.w;
        }
        __syncthreads();
        int p = t >> 1, cb = (t & 1) << 3;
        v8h o;
#pragma unroll
        for (int j = 0; j < 8; ++j) o[j] = (_Float16)lds[cb + j][p];
        _Float16* dst = (g < CV_K)
            ? (srcT + ((size_t)g * CV_HW + h * CV_W + p) * CV_C + cb)
            : (curT + ((size_t)h * CV_W + p) * CV_C + cb);
        *(v8h*)dst = o;
    }

    // ---- Phase B: projection matrices + depth params (redundant per block) ----
    if (t < CV_K * 12) {
        int k = t / 12, e = t % 12;
        const float* Km = Ks + k * 16;
        const float* E  = extr + k * 16;
        float s = 0.f;
        if (e < 9) {
            int i = e / 3, j = e % 3;
            for (int l = 0; l < 3; ++l) {
                float P = 0.f;
                for (int m = 0; m < 4; ++m) P += Km[i * 4 + m] * E[m * 4 + l];
                s += P * invK[l * 4 + j];
            }
        } else {
            int i = e - 9;
            for (int m = 0; m < 4; ++m) s += Km[i * 4 + m] * E[m * 4 + 3];
        }
        Ml[k][e] = s;
    }
    if (t == 255) {
        float mn = minD[0], mx = maxD[0];
        dparams[0] = logf(mn);
        dparams[1] = logf(mx / mn);
    }

    // ---- grid barrier (release srcT/curT writes, then acquire) ----
    __syncthreads();
    if (t == 0) {
        __threadfence();                       // writeback L2 (release)
        atomicAdd(counter, 1u);
        while (atomicAdd(counter, 0u) < CV_NBLK) {
            __builtin_amdgcn_s_sleep(2);
        }
        __threadfence();                       // invalidate caches (acquire)
    }
    __syncthreads();

    // ---- Phase C: cost volume ----
    const int wx = t & 7, hy = (t >> 3) & 7, dd = t >> 6;
    const int rem = b % 192;                   // 16 wb x 12 hb
    const int db2 = b / 192;                   // 4 depth super-blocks
    const int w = (rem & 15) * 8 + wx;
    const int h = (rem >> 4) * 8 + hy;
    const int dbase = db2 * 16 + dd * 4;       // this thread: depths dbase..dbase+3

    const float px = w + 0.5f;
    const float py = h + 0.5f;
    const float ld = dparams[0], lr = dparams[1];
    float dpt[4];
#pragma unroll
    for (int j = 0; j < 4; ++j)
        dpt[j] = expf(ld + lr * ((float)(dbase + j) * (1.0f / 63.0f)));

    const v8h* cp = (const v8h*)(curT + (h * CV_W + w) * CV_C);
    const v8h c0 = cp[0], c1 = cp[1];

    float acc[4] = {0.f, 0.f, 0.f, 0.f};
#pragma unroll
    for (int k = 0; k < CV_K; ++k) {
        const float* Mk = Ml[k];
        const float qx = Mk[0] * px + Mk[1] * py + Mk[2];
        const float qy = Mk[3] * px + Mk[4] * py + Mk[5];
        const float qz = Mk[6] * px + Mk[7] * py + Mk[8];
        const v8h* base = (const v8h*)srcT + (size_t)k * (CV_HW * 2);
#pragma unroll
        for (int j = 0; j < 4; ++j) {
            float depth = dpt[j];
            float cx = depth * qx + Mk[9];
            float cy = depth * qy + Mk[10];
            float cz = depth * qz + Mk[11];
            float valid = (cz > 0.f) ? 1.f : 0.f;
            float inv = 1.0f / (fabsf(cz) + CV_EPS);
            float x = fminf(fmaxf(cx * inv - 0.5f, -4.0f), (float)(CV_W + 3));
            float y = fminf(fmaxf(cy * inv - 0.5f, -4.0f), (float)(CV_H + 3));
            float xf = floorf(x), yf = floorf(y);
            float wx1 = x - xf, wy1 = y - yf;
            float wx0 = 1.f - wx1, wy0 = 1.f - wy1;
            int x0 = (int)xf, y0 = (int)yf;
            int x1 = x0 + 1, y1 = y0 + 1;
            bool vx0 = (unsigned)x0 < (unsigned)CV_W;
            bool vx1 = (unsigned)x1 < (unsigned)CV_W;
            bool vy0 = (unsigned)y0 < (unsigned)CV_H;
            bool vy1 = (unsigned)y1 < (unsigned)CV_H;
            int cx0 = min(max(x0, 0), CV_W - 1);
            int cx1 = min(max(x1, 0), CV_W - 1);
            int cy0 = min(max(y0, 0), CV_H - 1);
            int cy1 = min(max(y1, 0), CV_H - 1);
            const v8h* r0 = base + cy0 * (CV_W * 2);
            const v8h* r1 = base + cy1 * (CV_W * 2);
            v8h a00 = r0[cx0 * 2], b00 = r0[cx0 * 2 + 1];
            v8h a10 = r0[cx1 * 2], b10 = r0[cx1 * 2 + 1];
            v8h a01 = r1[cx0 * 2], b01 = r1[cx0 * 2 + 1];
            v8h a11 = r1[cx1 * 2], b11 = r1[cx1 * 2 + 1];
            float w00 = (vx0 && vy0) ? wx0 * wy0 : 0.f;
            float w10 = (vx1 && vy0) ? wx1 * wy0 : 0.f;
            float w01 = (vx0 && vy1) ? wx0 * wy1 : 0.f;
            float w11 = (vx1 && vy1) ? wx1 * wy1 : 0.f;
            float s = w00 * dot16h(a00, b00, c0, c1)
                    + w10 * dot16h(a10, b10, c0, c1)
                    + w01 * dot16h(a01, b01, c0, c1)
                    + w11 * dot16h(a11, b11, c0, c1);
            acc[j] = fmaf(valid, s, acc[j]);
        }
    }
#pragma unroll
    for (int j = 0; j < 4; ++j)
        out[((dbase + j) * CV_H + h) * CV_W + w] = acc[j];
}

extern "C" void kernel_launch(void* const* d_in, const int* in_sizes, int n_in,
                              void* d_out, int out_size, void* d_ws, size_t ws_size,
                              hipStream_t stream) {
    const float* cur_feats = (const float*)d_in[0];  // [1,16,96,128]
    const float* src_feats = (const float*)d_in[1];  // [1,7,16,96,128]
    const float* extr      = (const float*)d_in[2];  // [1,7,4,4]
    // d_in[3] = src_poses (unused)
    const float* Ks        = (const float*)d_in[4];  // [1,7,4,4]
    const float* invK      = (const float*)d_in[5];  // [1,4,4]
    const float* minD      = (const float*)d_in[6];
    const float* maxD      = (const float*)d_in[7];
    float* out = (float*)d_out;

    unsigned* counter = (unsigned*)d_ws;
    _Float16* srcT = (_Float16*)((char*)d_ws + 1024);      // [7,96,128,16] fp16
    _Float16* curT = srcT + (size_t)CV_K * CV_HW * CV_C;   // [96,128,16]  fp16

    // reset barrier counter every launch (capture-safe, deterministic)
    hipMemsetAsync(d_ws, 0, 4, stream);

    cv_fused<<<CV_NBLK, 256, 0, stream>>>(cur_feats, src_feats, extr, Ks, invK,
                                          minD, maxD, srcT, curT, counter, out);
}

// Round 5
// 33.074 us; speedup vs baseline: 2.8143x; 2.8143x over previous
//
#include <hip/hip_runtime.h>

#define CV_H 96
#define CV_W 128
#define CV_C 16
#define CV_K 7
#define CV_D 64
#define CV_EPS 1e-8f
#define CV_HW (CV_H * CV_W)

typedef _Float16 v2h __attribute__((ext_vector_type(2)));
typedef _Float16 v8h __attribute__((ext_vector_type(8)));

#if __has_builtin(__builtin_amdgcn_fdot2)
#define FDOT2(a, b, c) __builtin_amdgcn_fdot2((a), (b), (c), false)
#else
#define FDOT2(a, b, c) ((float)(a)[0] * (float)(b)[0] + (float)(a)[1] * (float)(b)[1] + (c))
#endif

// ---------------------------------------------------------------------------
// Prep (round-3 proven): blocks 0..(K+1)*H-1 LDS-transpose one (view,row)
// [C=16][W=128] f32 (coalesced float4 reads) -> [W][C] fp16 (coalesced v8h
// writes).  Last block: depth planes + fused projection matrices
// M[k]=[A|b], A=(Ks@E)[:3,:3]@invK[:3,:3], b=(Ks@E)[:3,3];
// cam = depth*(A@[x+.5,y+.5,1]) + b.
// ---------------------------------------------------------------------------
__global__ __launch_bounds__(256) void cv_prep(
    const float* __restrict__ cur, const float* __restrict__ src,
    const float* __restrict__ extr, const float* __restrict__ Ks,
    const float* __restrict__ invK, const float* __restrict__ minD,
    const float* __restrict__ maxD,
    float* __restrict__ depths, float* __restrict__ M,
    _Float16* __restrict__ srcT, _Float16* __restrict__ curT) {
    const int b = blockIdx.x;
    if (b == (CV_K + 1) * CV_H) {            // tiny setup block
        int t = threadIdx.x;
        if (t < CV_D) {
            float mn = minD[0], mx = maxD[0];
            float ramp = (float)t * (1.0f / (CV_D - 1));
            depths[t] = expf(logf(mn) + logf(mx / mn) * ramp);
        }
        if (t < CV_K) {
            const float* Km = Ks + t * 16;
            const float* E  = extr + t * 16;
            float P[3][4];
            for (int i = 0; i < 3; ++i)
                for (int j = 0; j < 4; ++j) {
                    float s = 0.f;
                    for (int l = 0; l < 4; ++l) s += Km[i * 4 + l] * E[l * 4 + j];
                    P[i][j] = s;
                }
            float* Mk = M + t * 12;
            for (int i = 0; i < 3; ++i)
                for (int j = 0; j < 3; ++j) {
                    float s = 0.f;
                    for (int l = 0; l < 3; ++l) s += P[i][l] * invK[l * 4 + j];
                    Mk[i * 3 + j] = s;
                }
            for (int i = 0; i < 3; ++i) Mk[9 + i] = P[i][3];
        }
        return;
    }
    const int g = b / CV_H;                  // 0..6 src views, 7 = cur
    const int h = b % CV_H;
    const float* rowBase = (g < CV_K) ? (src + (size_t)g * CV_C * CV_HW + h * CV_W)
                                      : (cur + h * CV_W);
    __shared__ float lds[CV_C][CV_W + 2];
    const int t = threadIdx.x;
#pragma unroll
    for (int i = 0; i < 2; ++i) {
        int f  = t + i * 256;                // float4 id, 0..511
        int c  = f >> 5;
        int w4 = (f & 31) << 2;
        float4 v = *(const float4*)(rowBase + (size_t)c * CV_HW + w4);
        lds[c][w4 + 0] = v.x; lds[c][w4 + 1] = v.y;
        lds[c][w4 + 2] = v.z; lds[c][w4 + 3] = v.w;
    }
    __syncthreads();
    const int p  = t >> 1;                   // pixel 0..127
    const int cb = (t & 1) << 3;             // channel half 0 / 8
    v8h o;
#pragma unroll
    for (int j = 0; j < 8; ++j) o[j] = (_Float16)lds[cb + j][p];
    _Float16* dst = (g < CV_K)
        ? (srcT + ((size_t)g * CV_HW + h * CV_W + p) * CV_C + cb)
        : (curT + ((size_t)h * CV_W + p) * CV_C + cb);
    *(v8h*)dst = o;
}

__device__ __forceinline__ float dot16h(v8h a0, v8h a1, v8h b0, v8h b1) {
    const v2h* pa0 = (const v2h*)&a0; const v2h* pb0 = (const v2h*)&b0;
    const v2h* pa1 = (const v2h*)&a1; const v2h* pb1 = (const v2h*)&b1;
    float s = 0.f;
#pragma unroll
    for (int i = 0; i < 4; ++i) s = FDOT2(pa0[i], pb0[i], s);
#pragma unroll
    for (int i = 0; i < 4; ++i) s = FDOT2(pa1[i], pb1[i], s);
    return s;
}

// ---------------------------------------------------------------------------
// Main: block = 8x8 px tile x 16 depths, 4 depths per thread (wave = full
// 8x8 tile at 4 adjacent depths -> tight L1 window).  Per view: q = A@pix
// and cur features hoisted across the 4 depth samples; branchless bilinear
// gather (8x b128 fp16 per view-depth); fast rcp for 1/z.
// ---------------------------------------------------------------------------
__global__ __launch_bounds__(256, 3) void cv_main(
    const _Float16* __restrict__ srcT,   // [K,H,W,C] fp16
    const _Float16* __restrict__ curT,   // [H,W,C]   fp16
    const float* __restrict__ depths,    // [D]
    const float* __restrict__ Mg,        // [K,12]
    float* __restrict__ out) {           // [D,H,W]
    const int bx  = blockIdx.x;          // 0..767
    const int rem = bx % 192;            // 16 wb x 12 hb
    const int db2 = bx / 192;            // 4 depth super-blocks
    const int t   = threadIdx.x;
    const int wx = t & 7, hy = (t >> 3) & 7, dd = t >> 6;
    const int w = (rem & 15) * 8 + wx;
    const int h = (rem >> 4) * 8 + hy;
    const int dbase = db2 * 16 + dd * 4; // this thread: depths dbase..dbase+3

    const float px = w + 0.5f;
    const float py = h + 0.5f;
    float dpt[4];
#pragma unroll
    for (int j = 0; j < 4; ++j) dpt[j] = depths[dbase + j];

    const v8h* cp = (const v8h*)(curT + (h * CV_W + w) * CV_C);
    const v8h c0 = cp[0], c1 = cp[1];

    float acc[4] = {0.f, 0.f, 0.f, 0.f};
#pragma unroll
    for (int k = 0; k < CV_K; ++k) {
        const float* Mk = Mg + k * 12;
        const float qx = Mk[0] * px + Mk[1] * py + Mk[2];
        const float qy = Mk[3] * px + Mk[4] * py + Mk[5];
        const float qz = Mk[6] * px + Mk[7] * py + Mk[8];
        const float bxk = Mk[9], byk = Mk[10], bzk = Mk[11];
        const v8h* base = (const v8h*)srcT + (size_t)k * (CV_HW * 2);
#pragma unroll
        for (int j = 0; j < 4; ++j) {
            float depth = dpt[j];
            float cx = fmaf(depth, qx, bxk);
            float cy = fmaf(depth, qy, byk);
            float cz = fmaf(depth, qz, bzk);
            float valid = (cz > 0.f) ? 1.f : 0.f;        // z>0 mask
            float inv = __builtin_amdgcn_rcpf(fabsf(cz) + CV_EPS);
            float x = fminf(fmaxf(fmaf(cx, inv, -0.5f), -4.0f), (float)(CV_W + 3));
            float y = fminf(fmaxf(fmaf(cy, inv, -0.5f), -4.0f), (float)(CV_H + 3));
            float xf = floorf(x), yf = floorf(y);
            float wx1 = x - xf, wy1 = y - yf;
            float wx0 = 1.f - wx1, wy0 = 1.f - wy1;
            int x0 = (int)xf, y0 = (int)yf;
            int x1 = x0 + 1, y1 = y0 + 1;
            bool vx0 = (unsigned)x0 < (unsigned)CV_W;
            bool vx1 = (unsigned)x1 < (unsigned)CV_W;
            bool vy0 = (unsigned)y0 < (unsigned)CV_H;
            bool vy1 = (unsigned)y1 < (unsigned)CV_H;
            int cx0 = min(max(x0, 0), CV_W - 1);
            int cx1 = min(max(x1, 0), CV_W - 1);
            int cy0 = min(max(y0, 0), CV_H - 1);
            int cy1 = min(max(y1, 0), CV_H - 1);
            const v8h* r0 = base + cy0 * (CV_W * 2);
            const v8h* r1 = base + cy1 * (CV_W * 2);
            v8h a00 = r0[cx0 * 2], b00 = r0[cx0 * 2 + 1];
            v8h a10 = r0[cx1 * 2], b10 = r0[cx1 * 2 + 1];
            v8h a01 = r1[cx0 * 2], b01 = r1[cx0 * 2 + 1];
            v8h a11 = r1[cx1 * 2], b11 = r1[cx1 * 2 + 1];
            float w00 = (vx0 && vy0) ? wx0 * wy0 : 0.f;
            float w10 = (vx1 && vy0) ? wx1 * wy0 : 0.f;
            float w01 = (vx0 && vy1) ? wx0 * wy1 : 0.f;
            float w11 = (vx1 && vy1) ? wx1 * wy1 : 0.f;
            float s = w00 * dot16h(a00, b00, c0, c1)
                    + w10 * dot16h(a10, b10, c0, c1)
                    + w01 * dot16h(a01, b01, c0, c1)
                    + w11 * dot16h(a11, b11, c0, c1);
            acc[j] = fmaf(valid, s, acc[j]);
        }
    }
#pragma unroll
    for (int j = 0; j < 4; ++j)
        out[((dbase + j) * CV_H + h) * CV_W + w] = acc[j];
}

extern "C" void kernel_launch(void* const* d_in, const int* in_sizes, int n_in,
                              void* d_out, int out_size, void* d_ws, size_t ws_size,
                              hipStream_t stream) {
    const float* cur_feats = (const float*)d_in[0];  // [1,16,96,128]
    const float* src_feats = (const float*)d_in[1];  // [1,7,16,96,128]
    const float* extr      = (const float*)d_in[2];  // [1,7,4,4]
    // d_in[3] = src_poses (unused)
    const float* Ks        = (const float*)d_in[4];  // [1,7,4,4]
    const float* invK      = (const float*)d_in[5];  // [1,4,4]
    const float* minD      = (const float*)d_in[6];
    const float* maxD      = (const float*)d_in[7];
    float* out = (float*)d_out;

    float* wsf    = (float*)d_ws;
    float* depths = wsf;                       // 64 floats
    float* M      = wsf + 64;                  // 84 floats
    _Float16* srcT = (_Float16*)(wsf + 256);   // [7,96,128,16] fp16
    _Float16* curT = srcT + (size_t)CV_K * CV_HW * CV_C;

    cv_prep<<<(CV_K + 1) * CV_H + 1, 256, 0, stream>>>(
        cur_feats, src_feats, extr, Ks, invK, minD, maxD, depths, M, srcT, curT);

    cv_main<<<(CV_D / 16) * (CV_H / 8) * (CV_W / 8), 256, 0, stream>>>(
        srcT, curT, depths, M, out);
}